// Round 5
// baseline (371.718 us; speedup 1.0000x reference)
//
#include <hip/hip_runtime.h>

typedef unsigned short ushort;
typedef unsigned int uint;
typedef __attribute__((ext_vector_type(8))) short short8;
typedef __attribute__((ext_vector_type(4))) float f32x4;

#define B_    8192
#define NB_   2
#define GRID_ (B_ / NB_)
#define D_    128
#define K_    32
#define NV_   50000
#define SC_   28.853900817779268f   /* log2(e)/eps */
#define ISC_  0.03465735902799726f  /* eps*ln2     */

/* ws float offsets */
#define WS_HF    0
#define WS_LHF2  16
#define WS_CCT   32
#define WS_CC2T  544
#define WS_F2    1056
#define WS_W1T   1568            /* 4096 floats: w1T[u][d] */
/* ws byte offsets */
#define WSB_FBHI 22656
#define WSB_FBLO 153728
#define WSB_CB1  284800

__device__ __forceinline__ ushort bf16rne(float v) {
    uint u = __float_as_uint(v);
    uint r = (u + 0x7fffu + ((u >> 16) & 1u)) >> 16;
    return (ushort)r;
}
__device__ __forceinline__ float bf16tof(ushort h) { return __uint_as_float(((uint)h) << 16); }

template <int C>
__device__ __forceinline__ float dppmv(float x) {
    return __int_as_float(__builtin_amdgcn_update_dpp(
        __float_as_int(x), __float_as_int(x), C, 0xf, 0xf, false));
}
__device__ __forceinline__ float rowmax16(float x) {
    x = fmaxf(x, dppmv<0x121>(x));
    x = fmaxf(x, dppmv<0x122>(x));
    x = fmaxf(x, dppmv<0x124>(x));
    x = fmaxf(x, dppmv<0x128>(x));
    return x;
}
__device__ __forceinline__ float rowsum16(float x) {
    x += dppmv<0x121>(x);
    x += dppmv<0x122>(x);
    x += dppmv<0x124>(x);
    x += dppmv<0x128>(x);
    return x;
}
__device__ __forceinline__ f32x4 mfma16(short8 a, short8 b, f32x4 c) {
    return __builtin_amdgcn_mfma_f32_16x16x32_bf16(a, b, c, 0, 0, 0);
}
__device__ __forceinline__ uint cvtpk_bf16(float a, float b) {
    uint r;
    asm("v_cvt_pk_bf16_f32 %0, %1, %2" : "=v"(r) : "v"(a), "v"(b));
    return r;
}

/* ---- init: F fragments (hi/lo split, B-frag order) ---- */
__global__ __launch_bounds__(512) void init_fb(const float* __restrict__ Ff, float* __restrict__ ws) {
    int idx = blockIdx.x * 512 + threadIdx.x;  /* [0, 65536) */
    int e = idx & 7, l = (idx >> 3) & 63, s = (idx >> 9) & 3, k = idx >> 11;
    int j = l & 15, kg = l >> 4;
    int d = s * 32 + kg * 8 + e;
    float v = Ff[(j * D_ + d) * K_ + k];
    ushort hb = bf16rne(v);
    ushort lb = bf16rne(v - bf16tof(hb));
    ushort* FBHI = (ushort*)((char*)ws + WSB_FBHI);
    ushort* FBLO = (ushort*)((char*)ws + WSB_FBLO);
    FBHI[idx] = hb;
    FBLO[idx] = lb;
}

/* ---- init: hf, cct, cc2t, f2, w1T, C fragments ---- */
__global__ __launch_bounds__(1024) void init_small(
    const float* __restrict__ C_up, const float* __restrict__ Ff,
    const float* __restrict__ h_logits, const float* __restrict__ w1,
    float* __restrict__ ws) {
    __shared__ float hf[16];
    __shared__ float Cs[16][16][32];
    __shared__ float f2p[16][32][2];
    const int t = threadIdx.x;

    if (t == 0) {
        float m = -3.4e38f;
        for (int p = 0; p < 16; ++p) m = fmaxf(m, h_logits[p]);
        float e[16], s = 0.f;
        for (int p = 0; p < 16; ++p) { e[p] = __expf(h_logits[p] - m); s += e[p]; }
        for (int p = 0; p < 16; ++p) {
            hf[p] = e[p] / s;
            ws[WS_HF + p] = hf[p];
            ws[WS_LHF2 + p] = log2f(hf[p]);
        }
    }
    for (int e0 = t; e0 < 16 * 16 * 32; e0 += 1024) {
        int k = e0 & 31, j = (e0 >> 5) & 15, q = e0 >> 9;
        float v = 0.f;
        if (q < j)      { int pi = q * (31 - q) / 2 + (j - q - 1); v = fmaxf(C_up[pi * 32 + k], 0.f); }
        else if (j < q) { int pi = j * (31 - j) / 2 + (q - j - 1); v = fmaxf(C_up[pi * 32 + k], 0.f); }
        Cs[q][j][k] = v;
    }
    for (int e0 = t; e0 < 4096; e0 += 1024) {
        int u = e0 >> 7, d = e0 & 127;
        ws[WS_W1T + e0] = w1[d * 32 + u];
    }
    __syncthreads();

    if (t < 512) {
        int k = t >> 4, j = t & 15;
        float s1 = 0.f, s2 = 0.f;
        for (int q = 0; q < 16; ++q) {
            float c = Cs[q][j][k];
            s1 += hf[q] * c;
            s2 += hf[q] * c * c;
        }
        ws[WS_CCT + k * 16 + j] = s1;
        ws[WS_CC2T + k * 16 + j] = s2;
    }
    {
        int k = t & 31, half = (t >> 5) & 1, j = t >> 6;
        float s = 0.f;
        for (int dd = 0; dd < 64; ++dd) {
            int d = half * 64 + dd;
            float f = Ff[(j * D_ + d) * K_ + k];
            s += f * f;
        }
        f2p[j][k][half] = s;
    }
    {
        ushort* CB1 = (ushort*)((char*)ws + WSB_CB1);
        for (int i0 = t; i0 < 16384; i0 += 1024) {
            int e = i0 & 7, l = (i0 >> 3) & 63, k = i0 >> 9;
            int kg = l >> 4, j = l & 15, q = (kg & 1) * 8 + e;
            /* kg<2: C_hi[q][j]; kg>=2: 0 (pairs with zeroed tmp-lo half) */
            CB1[i0] = (kg < 2) ? bf16rne(Cs[q][j][k]) : (ushort)0;
        }
    }
    __syncthreads();
    if (t < 512) {
        int j = t >> 5, k = t & 31;
        ws[WS_F2 + j * 32 + k] = f2p[j][k][0] + f2p[j][k][1];
    }
}

/* ---- main: 1024-thread block (16 waves = 4 waves/SIMD resident), NB_=2 graphs ---- */
__global__ __launch_bounds__(1024, 4) void fgw_main(
    const float* __restrict__ adj, const float* __restrict__ features,
    const int* __restrict__ idxs,
    const float* __restrict__ b1,
    const float* __restrict__ w2, const float* __restrict__ b2,
    const float* __restrict__ ws, float* __restrict__ out) {
    __shared__ __align__(16) ushort xA[NB_][2][4][64][8];   /* 16 KB */
    __shared__ __align__(16) uint  exchbuf[6144];           /* 24 KB; setup overlay = xT (4224 fl) */
    __shared__ __align__(16) ushort adjA[NB_][64][8];       /* 2 KB  */
    __shared__ float cct_s[512];                            /* [k][j] */
    __shared__ float cc2_s[512];                            /* [k][j] */
    __shared__ float f2_s[16][33];                          /* [j][k] padded */
    __shared__ float lhf_s[16];
    __shared__ float adj_s[NB_][16][17];
    __shared__ float pooled[NB_][128];
    __shared__ float x2part[NB_][16][8];
    __shared__ __align__(16) float x2s[NB_][16];
    __shared__ __align__(16) float c1s[NB_][16];
    __shared__ __align__(16) float rss[NB_][16];            /* pre-scaled by 1/16 */
    __shared__ float alpha_sh[NB_];
    __shared__ int idx_sh[NB_][16];

    const int t = threadIdx.x;
    const int blk = blockIdx.x;
    float* xT = (float*)exchbuf;  /* [NB_][16][132] overlay, setup only */

    /* stage per-k tables into LDS; upper 512 threads load adj */
    if (t < 512) {
        cct_s[t] = ws[WS_CCT + t];
        cc2_s[t] = ws[WS_CC2T + t];
        f2_s[t >> 5][t & 31] = ws[WS_F2 + t];
    } else {
        int t2 = t - 512;
        int pb = t2 >> 8, rem = t2 & 255;
        adj_s[pb][rem >> 4][rem & 15] = adj[(blk * NB_ + pb) * 256 + rem];
    }
    if (t < 16) lhf_s[t] = ws[WS_LHF2 + t];
    if (t < NB_ * 16) idx_sh[t >> 4][t & 15] = idxs[(blk * NB_ + (t >> 4)) * 16 + (t & 15)];
    __syncthreads();

    if (t < 256) {
        int pb = t >> 7, i = (t >> 3) & 15, c = t & 7;
        int ix = idx_sh[pb][i];
        float vv[16];
        if (ix < NV_) {
            const float4* fp = (const float4*)(features + (size_t)ix * D_ + c * 16);
            float4 q0 = fp[0], q1 = fp[1], q2 = fp[2], q3 = fp[3];
            vv[0] = q0.x; vv[1] = q0.y; vv[2] = q0.z; vv[3] = q0.w;
            vv[4] = q1.x; vv[5] = q1.y; vv[6] = q1.z; vv[7] = q1.w;
            vv[8] = q2.x; vv[9] = q2.y; vv[10] = q2.z; vv[11] = q2.w;
            vv[12] = q3.x; vv[13] = q3.y; vv[14] = q3.z; vv[15] = q3.w;
        } else {
            #pragma unroll
            for (int e = 0; e < 16; ++e) vv[e] = 0.f;
        }
        float* xrow = xT + (pb * 16 + i) * 132 + c * 16;
        float s2 = 0.f;
        #pragma unroll
        for (int e = 0; e < 16; ++e) { xrow[e] = vv[e]; s2 += vv[e] * vv[e]; }
        x2part[pb][i][c] = s2;
        #pragma unroll
        for (int g = 0; g < 2; ++g) {
            int d0 = c * 16 + g * 8;
            int s = d0 >> 5, kg = (d0 >> 3) & 3;
            union { short8 v; ushort u[8]; } h8, l8;
            #pragma unroll
            for (int e = 0; e < 8; ++e) {
                float x = vv[g * 8 + e];
                ushort hb = bf16rne(x);
                h8.u[e] = hb;
                l8.u[e] = bf16rne(x - bf16tof(hb));
            }
            *(short8*)&xA[pb][0][s][kg * 16 + i][0] = h8.v;
            *(short8*)&xA[pb][1][s][kg * 16 + i][0] = l8.v;
        }
    } else if (t < 384) {
        int t2 = t - 256, pb = t2 >> 6, l = t2 & 63;
        int i = l & 15, kg = l >> 4;
        union { short8 v; ushort u[8]; } f8;
        #pragma unroll
        for (int e = 0; e < 8; ++e) {
            int p = (kg & 1) * 8 + e;
            float v = adj_s[pb][i][p];
            ushort hb = bf16rne(v);
            f8.u[e] = (kg < 2) ? hb : bf16rne(v - bf16tof(hb));
        }
        *(short8*)&adjA[pb][l][0] = f8.v;
    } else if (t < 416) {
        int t2 = t - 384, pb = t2 >> 4, i = t2 & 15;
        float s = 0.f, s2 = 0.f;
        for (int p = 0; p < 16; ++p) { float a = adj_s[pb][i][p]; s += a; s2 += a * a; }
        rss[pb][i] = s * (1.f / 16.f);
        c1s[pb][i] = s2 * (1.f / 16.f);
    }
    __syncthreads();

    if (t < NB_ * 128) {
        int pb = t >> 7, d = t & 127;
        float s = 0.f;
        for (int i = 0; i < 16; ++i) s += xT[(pb * 16 + i) * 132 + d];
        pooled[pb][d] = s * (1.f / 16.f);
    } else if (t < NB_ * 128 + NB_ * 16) {
        int t2 = t - NB_ * 128, pb = t2 >> 4, i = t2 & 15;
        float s = 0.f;
        #pragma unroll
        for (int c = 0; c < 8; ++c) s += x2part[pb][i][c];
        x2s[pb][i] = s;
    }
    __syncthreads();

    if (t < 64) {
        int pb = t >> 5, u = t & 31;
        float h = b1[u];
        const float4* wrow = (const float4*)(ws + WS_W1T + u * 128);
        #pragma unroll 4
        for (int dd = 0; dd < 32; ++dd) {
            float4 w4 = wrow[dd];
            h = fmaf(pooled[pb][dd * 4 + 0], w4.x, h);
            h = fmaf(pooled[pb][dd * 4 + 1], w4.y, h);
            h = fmaf(pooled[pb][dd * 4 + 2], w4.z, h);
            h = fmaf(pooled[pb][dd * 4 + 3], w4.w, h);
        }
        h = fmaxf(h, 0.f);
        float z = h * w2[u];
        #pragma unroll
        for (int s = 1; s < 32; s <<= 1) z += __shfl_xor(z, s);
        if (u == 0) alpha_sh[pb] = 1.f / (1.f + __expf(-(z + b2[0])));
    }
    __syncthreads();

    /* ---- fused per-kk: xf MFMA -> sinkhorn -> gw_tens -> out ---- */
    const int w = t >> 6, l = t & 63;       /* w in [0,16) */
    const int jl = l & 15, ig = l >> 4;
    const float lq2 = lhf_s[jl];
    const ushort* FBHI = (const ushort*)((const char*)ws + WSB_FBHI);
    const ushort* FBLO = (const ushort*)((const char*)ws + WSB_FBLO);
    const ushort* CB1  = (const ushort*)((const char*)ws + WSB_CB1);
    uint* Tb = exchbuf + w * 384;        /* 16 x 12 uints */
    uint* Mb = Tb + 192;                 /* 16 x 24 ushorts */

    #pragma unroll 1
    for (int kk = 0; kk < 2; ++kk) {
        const int k = kk * 16 + w;
        f32x4 acc0 = {0.f, 0.f, 0.f, 0.f}, acc1 = {0.f, 0.f, 0.f, 0.f};
        #pragma unroll
        for (int s = 0; s < 4; ++s) {
            const short8 Bh = *(const short8*)(FBHI + ((k * 4 + s) * 64 + l) * 8);
            const short8 Bl = *(const short8*)(FBLO + ((k * 4 + s) * 64 + l) * 8);
            {
                const short8 Ah = *(const short8*)&xA[0][0][s][l][0];
                const short8 Al = *(const short8*)&xA[0][1][s][l][0];
                acc0 = mfma16(Ah, Bh, acc0);
                acc0 = mfma16(Al, Bh, acc0);
                acc0 = mfma16(Ah, Bl, acc0);
            }
            {
                const short8 Ah = *(const short8*)&xA[1][0][s][l][0];
                const short8 Al = *(const short8*)&xA[1][1][s][l][0];
                acc1 = mfma16(Ah, Bh, acc1);
                acc1 = mfma16(Al, Bh, acc1);
                acc1 = mfma16(Ah, Bl, acc1);
            }
        }
        const float f2v  = f2_s[jl][k];
        const float cctv = cct_s[k * 16 + jl];
        const float cc2v = cc2_s[k * 16 + jl];
        const short8 C1f = *(const short8*)(CB1 + (k * 64 + l) * 8);

        #pragma unroll
        for (int pb = 0; pb < NB_; ++pb) {
            const f32x4 accv = pb ? acc1 : acc0;
            const float alpha = alpha_sh[pb], oma = 1.f - alpha;
            const short8 Aadj = *(const short8*)&adjA[pb][l][0];
            const f32x4 x2v = *(const f32x4*)&x2s[pb][ig * 4];
            const f32x4 c1v = *(const f32x4*)&c1s[pb][ig * 4];
            const f32x4 rsv = *(const f32x4*)&rss[pb][ig * 4];
            float Chat[4], rc[4];
            #pragma unroll
            for (int r = 0; r < 4; ++r) {
                float M = x2v[r] + f2v - 2.f * accv[r];
                rc[r] = rsv[r] * cctv;
                float gw0 = c1v[r] + cc2v - 2.f * rc[r];
                Chat[r] = SC_ * (oma * M + alpha * gw0);
            }
            /* log2-domain sinkhorn, 2 iters; h_sub=1/16 -> lp2=-4 */
            float G = 0.f, Fh[4];
            #pragma unroll
            for (int it = 0; it < 2; ++it) {
                #pragma unroll
                for (int r = 0; r < 4; ++r) {
                    float a = G - Chat[r];
                    float m = rowmax16(a);
                    float e = exp2f(a - m);
                    float S = rowsum16(e);
                    Fh[r] = -4.f - m - log2f(S);
                }
                float diff[4];
                #pragma unroll
                for (int r = 0; r < 4; ++r) diff[r] = Fh[r] - Chat[r];
                float m2 = fmaxf(fmaxf(diff[0], diff[1]), fmaxf(diff[2], diff[3]));
                m2 = fmaxf(m2, __shfl_xor(m2, 16));
                m2 = fmaxf(m2, __shfl_xor(m2, 32));
                float S2 = 0.f;
                #pragma unroll
                for (int r = 0; r < 4; ++r) S2 += exp2f(diff[r] - m2);
                S2 += __shfl_xor(S2, 16);
                S2 += __shfl_xor(S2, 32);
                G = lq2 - m2 - log2f(S2);
            }
            float Tv[4];
            #pragma unroll
            for (int r = 0; r < 4; ++r) Tv[r] = exp2f(Fh[r] + G - Chat[r]);

            /* T exchange: packed bf16 via v_cvt_pk. Tb[col*12 + row/2] */
            Tb[jl * 12 + ig * 2]     = cvtpk_bf16(Tv[0], Tv[1]);
            Tb[jl * 12 + ig * 2 + 1] = cvtpk_bf16(Tv[2], Tv[3]);
            /* B-frag: lane (kg=ig, j=jl) needs T[(ig&1)*8 + e][jl] */
            const short8 Bt = *(const short8*)&Tb[jl * 12 + (ig & 1) * 4];
            f32x4 tmpv = mfma16(Aadj, Bt, (f32x4){0.f, 0.f, 0.f, 0.f});

            /* tmp exchange: bf16 row-major [16][24] ushorts */
            ushort* Mbs = (ushort*)Mb;
            #pragma unroll
            for (int r = 0; r < 4; ++r)
                Mbs[(ig * 4 + r) * 24 + jl] = bf16rne(tmpv[r]);
            const short8 Atm = *(const short8*)&Mbs[jl * 24 + (ig & 1) * 8];
            f32x4 cr = mfma16(Atm, C1f, (f32x4){0.f, 0.f, 0.f, 0.f});

            float dot = 0.f;
            #pragma unroll
            for (int r = 0; r < 4; ++r) {
                float fc = Chat[r] * ISC_ + 2.f * alpha * (rc[r] - cr[r]);
                dot = fmaf(Tv[r], fc, dot);
            }
            dot = rowsum16(dot);
            dot += __shfl_xor(dot, 16);
            dot += __shfl_xor(dot, 32);
            if (l == 0) out[(blk * NB_ + pb) * K_ + k] = dot;
        }
    }
}

extern "C" void kernel_launch(void* const* d_in, const int* in_sizes, int n_in,
                              void* d_out, int out_size, void* d_ws, size_t ws_size,
                              hipStream_t stream) {
    (void)in_sizes; (void)n_in; (void)out_size; (void)ws_size;
    const float* adj      = (const float*)d_in[0];
    const float* features = (const float*)d_in[1];
    const int*   idxs     = (const int*)  d_in[2];
    const float* C_up     = (const float*)d_in[3];
    const float* Ff       = (const float*)d_in[4];
    const float* h_logits = (const float*)d_in[5];
    const float* w1       = (const float*)d_in[6];
    const float* b1       = (const float*)d_in[7];
    const float* w2       = (const float*)d_in[8];
    const float* b2       = (const float*)d_in[9];
    float* out = (float*)d_out;
    float* ws  = (float*)d_ws;

    hipLaunchKernelGGL(init_fb, dim3(128), dim3(512), 0, stream, Ff, ws);
    hipLaunchKernelGGL(init_small, dim3(1), dim3(1024), 0, stream, C_up, Ff, h_logits, w1, ws);
    hipLaunchKernelGGL(fgw_main, dim3(GRID_), dim3(1024), 0, stream,
                       adj, features, idxs, b1, w2, b2, ws, out);
}

// Round 6
// 289.074 us; speedup vs baseline: 1.2859x; 1.2859x over previous
//
#include <hip/hip_runtime.h>

typedef unsigned short ushort;
typedef unsigned int uint;
typedef __attribute__((ext_vector_type(8))) short short8;
typedef __attribute__((ext_vector_type(4))) float f32x4;

#define B_    8192
#define D_    128
#define K_    32
#define NV_   50000
#define SC_   28.853900817779268f   /* log2(e)/eps */
#define ISC_  0.03465735902799726f  /* eps*ln2     */

/* ws float offsets */
#define WS_HF    0
#define WS_LHF2  16
#define WS_CCT   32
#define WS_CC2T  544
#define WS_F2    1056
#define WS_W1T   1568            /* 4096 floats: w1T[u][d] */
/* ws byte offsets */
#define WSB_FBHI 22656
#define WSB_FBLO 153728
#define WSB_CB1  284800

__device__ __forceinline__ ushort bf16rne(float v) {
    uint u = __float_as_uint(v);
    uint r = (u + 0x7fffu + ((u >> 16) & 1u)) >> 16;
    return (ushort)r;
}
__device__ __forceinline__ float bf16tof(ushort h) { return __uint_as_float(((uint)h) << 16); }

template <int C>
__device__ __forceinline__ float dppmv(float x) {
    return __int_as_float(__builtin_amdgcn_update_dpp(
        __float_as_int(x), __float_as_int(x), C, 0xf, 0xf, false));
}
__device__ __forceinline__ float rowmax16(float x) {
    x = fmaxf(x, dppmv<0x121>(x));
    x = fmaxf(x, dppmv<0x122>(x));
    x = fmaxf(x, dppmv<0x124>(x));
    x = fmaxf(x, dppmv<0x128>(x));
    return x;
}
__device__ __forceinline__ float rowsum16(float x) {
    x += dppmv<0x121>(x);
    x += dppmv<0x122>(x);
    x += dppmv<0x124>(x);
    x += dppmv<0x128>(x);
    return x;
}
__device__ __forceinline__ f32x4 mfma16(short8 a, short8 b, f32x4 c) {
    return __builtin_amdgcn_mfma_f32_16x16x32_bf16(a, b, c, 0, 0, 0);
}
__device__ __forceinline__ uint cvtpk_bf16(float a, float b) {
    uint r;
    asm("v_cvt_pk_bf16_f32 %0, %1, %2" : "=v"(r) : "v"(a), "v"(b));
    return r;
}

/* ---- init: F fragments (hi/lo split, B-frag order) ---- */
__global__ __launch_bounds__(512) void init_fb(const float* __restrict__ Ff, float* __restrict__ ws) {
    int idx = blockIdx.x * 512 + threadIdx.x;  /* [0, 65536) */
    int e = idx & 7, l = (idx >> 3) & 63, s = (idx >> 9) & 3, k = idx >> 11;
    int j = l & 15, kg = l >> 4;
    int d = s * 32 + kg * 8 + e;
    float v = Ff[(j * D_ + d) * K_ + k];
    ushort hb = bf16rne(v);
    ushort lb = bf16rne(v - bf16tof(hb));
    ushort* FBHI = (ushort*)((char*)ws + WSB_FBHI);
    ushort* FBLO = (ushort*)((char*)ws + WSB_FBLO);
    FBHI[idx] = hb;
    FBLO[idx] = lb;
}

/* ---- init: hf, cct, cc2t, f2, w1T, C fragments ---- */
__global__ __launch_bounds__(1024) void init_small(
    const float* __restrict__ C_up, const float* __restrict__ Ff,
    const float* __restrict__ h_logits, const float* __restrict__ w1,
    float* __restrict__ ws) {
    __shared__ float hf[16];
    __shared__ float Cs[16][16][32];
    __shared__ float f2p[16][32][2];
    const int t = threadIdx.x;

    if (t == 0) {
        float m = -3.4e38f;
        for (int p = 0; p < 16; ++p) m = fmaxf(m, h_logits[p]);
        float e[16], s = 0.f;
        for (int p = 0; p < 16; ++p) { e[p] = __expf(h_logits[p] - m); s += e[p]; }
        for (int p = 0; p < 16; ++p) {
            hf[p] = e[p] / s;
            ws[WS_HF + p] = hf[p];
            ws[WS_LHF2 + p] = log2f(hf[p]);
        }
    }
    for (int e0 = t; e0 < 16 * 16 * 32; e0 += 1024) {
        int k = e0 & 31, j = (e0 >> 5) & 15, q = e0 >> 9;
        float v = 0.f;
        if (q < j)      { int pi = q * (31 - q) / 2 + (j - q - 1); v = fmaxf(C_up[pi * 32 + k], 0.f); }
        else if (j < q) { int pi = j * (31 - j) / 2 + (q - j - 1); v = fmaxf(C_up[pi * 32 + k], 0.f); }
        Cs[q][j][k] = v;
    }
    for (int e0 = t; e0 < 4096; e0 += 1024) {
        int u = e0 >> 7, d = e0 & 127;
        ws[WS_W1T + e0] = w1[d * 32 + u];
    }
    __syncthreads();

    if (t < 512) {
        int k = t >> 4, j = t & 15;
        float s1 = 0.f, s2 = 0.f;
        for (int q = 0; q < 16; ++q) {
            float c = Cs[q][j][k];
            s1 += hf[q] * c;
            s2 += hf[q] * c * c;
        }
        ws[WS_CCT + k * 16 + j] = s1;
        ws[WS_CC2T + k * 16 + j] = s2;
    }
    {
        int k = t & 31, half = (t >> 5) & 1, j = t >> 6;
        float s = 0.f;
        for (int dd = 0; dd < 64; ++dd) {
            int d = half * 64 + dd;
            float f = Ff[(j * D_ + d) * K_ + k];
            s += f * f;
        }
        f2p[j][k][half] = s;
    }
    {
        ushort* CB1 = (ushort*)((char*)ws + WSB_CB1);
        for (int i0 = t; i0 < 16384; i0 += 1024) {
            int e = i0 & 7, l = (i0 >> 3) & 63, k = i0 >> 9;
            int kg = l >> 4, j = l & 15, q = (kg & 1) * 8 + e;
            /* kg<2: C_hi[q][j]; kg>=2: 0 (pairs with duplicated tmp rows) */
            CB1[i0] = (kg < 2) ? bf16rne(Cs[q][j][k]) : (ushort)0;
        }
    }
    __syncthreads();
    if (t < 512) {
        int j = t >> 5, k = t & 31;
        ws[WS_F2 + j * 32 + k] = f2p[j][k][0] + f2p[j][k][1];
    }
}

/* ---- main: 256-thread block (4 waves), ONE graph per block, 8 k per wave ---- */
__global__ __launch_bounds__(256, 4) void fgw_main(
    const float* __restrict__ adj, const float* __restrict__ features,
    const int* __restrict__ idxs,
    const float* __restrict__ b1,
    const float* __restrict__ w2, const float* __restrict__ b2,
    const float* __restrict__ ws, float* __restrict__ out) {
    __shared__ __align__(16) ushort xA[2][4][64][8];   /* 8 KB: hi/lo, s, lane, 8 */
    __shared__ __align__(16) uint  exchbuf[2112];      /* 8.25 KB; setup overlay = xT[16][132] */
    __shared__ __align__(16) ushort adjA[64][8];       /* 1 KB */
    __shared__ float cct_s[512];                       /* [k][j] */
    __shared__ float cc2_s[512];                       /* [k][j] */
    __shared__ float f2_s[16][33];                     /* [j][k] padded */
    __shared__ float lhf_s[16];
    __shared__ float adj_s[16][17];
    __shared__ float pooled[128];
    __shared__ float x2part[16][8];
    __shared__ __align__(16) float x2s[16];
    __shared__ __align__(16) float c1s[16];
    __shared__ __align__(16) float rss[16];            /* pre-scaled by 1/16 */
    __shared__ float alpha_sh;
    __shared__ int idx_sh[16];

    const int t = threadIdx.x;
    const int blk = blockIdx.x;
    float* xT = (float*)exchbuf;  /* [16][132] overlay, setup only */

    /* stage per-k tables + adj + idx */
    #pragma unroll
    for (int e = t; e < 512; e += 256) {
        cct_s[e] = ws[WS_CCT + e];
        cc2_s[e] = ws[WS_CC2T + e];
        f2_s[e >> 5][e & 31] = ws[WS_F2 + e];
    }
    adj_s[t >> 4 & 15][t & 15] = adj[blk * 256 + (t & 255)];
    if (t < 16) {
        lhf_s[t] = ws[WS_LHF2 + t];
        idx_sh[t] = idxs[blk * 16 + t];
    }
    __syncthreads();

    if (t < 128) {
        int i = t >> 3, c = t & 7;
        int ix = idx_sh[i];
        float vv[16];
        if (ix < NV_) {
            const float4* fp = (const float4*)(features + (size_t)ix * D_ + c * 16);
            float4 q0 = fp[0], q1 = fp[1], q2 = fp[2], q3 = fp[3];
            vv[0] = q0.x; vv[1] = q0.y; vv[2] = q0.z; vv[3] = q0.w;
            vv[4] = q1.x; vv[5] = q1.y; vv[6] = q1.z; vv[7] = q1.w;
            vv[8] = q2.x; vv[9] = q2.y; vv[10] = q2.z; vv[11] = q2.w;
            vv[12] = q3.x; vv[13] = q3.y; vv[14] = q3.z; vv[15] = q3.w;
        } else {
            #pragma unroll
            for (int e = 0; e < 16; ++e) vv[e] = 0.f;
        }
        float* xrow = xT + i * 132 + c * 16;
        float s2 = 0.f;
        #pragma unroll
        for (int e = 0; e < 16; ++e) { xrow[e] = vv[e]; s2 += vv[e] * vv[e]; }
        x2part[i][c] = s2;
        #pragma unroll
        for (int g = 0; g < 2; ++g) {
            int d0 = c * 16 + g * 8;
            int s = d0 >> 5, kg = (d0 >> 3) & 3;
            union { short8 v; ushort u[8]; } h8, l8;
            #pragma unroll
            for (int e = 0; e < 8; ++e) {
                float x = vv[g * 8 + e];
                ushort hb = bf16rne(x);
                h8.u[e] = hb;
                l8.u[e] = bf16rne(x - bf16tof(hb));
            }
            *(short8*)&xA[0][s][kg * 16 + i][0] = h8.v;
            *(short8*)&xA[1][s][kg * 16 + i][0] = l8.v;
        }
    } else if (t < 192) {
        int l = t - 128;
        int i = l & 15, kg = l >> 4;
        union { short8 v; ushort u[8]; } f8;
        #pragma unroll
        for (int e = 0; e < 8; ++e) {
            int p = (kg & 1) * 8 + e;
            float v = adj_s[i][p];
            ushort hb = bf16rne(v);
            f8.u[e] = (kg < 2) ? hb : bf16rne(v - bf16tof(hb));
        }
        *(short8*)&adjA[l][0] = f8.v;
    } else if (t < 208) {
        int i = t - 192;
        float s = 0.f, s2 = 0.f;
        for (int p = 0; p < 16; ++p) { float a = adj_s[i][p]; s += a; s2 += a * a; }
        rss[i] = s * (1.f / 16.f);
        c1s[i] = s2 * (1.f / 16.f);
    }
    __syncthreads();

    if (t < 128) {
        int d = t;
        float s = 0.f;
        for (int i = 0; i < 16; ++i) s += xT[i * 132 + d];
        pooled[d] = s * (1.f / 16.f);
    } else if (t < 144) {
        int i = t - 128;
        float s = 0.f;
        #pragma unroll
        for (int c = 0; c < 8; ++c) s += x2part[i][c];
        x2s[i] = s;
    }
    __syncthreads();

    if (t < 32) {
        int u = t;
        float h = b1[u];
        const float4* wrow = (const float4*)(ws + WS_W1T + u * 128);
        #pragma unroll 4
        for (int dd = 0; dd < 32; ++dd) {
            float4 w4 = wrow[dd];
            h = fmaf(pooled[dd * 4 + 0], w4.x, h);
            h = fmaf(pooled[dd * 4 + 1], w4.y, h);
            h = fmaf(pooled[dd * 4 + 2], w4.z, h);
            h = fmaf(pooled[dd * 4 + 3], w4.w, h);
        }
        h = fmaxf(h, 0.f);
        float z = h * w2[u];
        #pragma unroll
        for (int s = 1; s < 32; s <<= 1) z += __shfl_xor(z, s);
        if (u == 0) alpha_sh = 1.f / (1.f + __expf(-(z + b2[0])));
    }
    __syncthreads();

    /* ---- fused per-kk: xf MFMA -> sinkhorn -> gw_tens -> out ---- */
    const int w = t >> 6, l = t & 63;       /* w in [0,4) */
    const int jl = l & 15, ig = l >> 4;
    const float lq2 = lhf_s[jl];
    const ushort* FBHI = (const ushort*)((const char*)ws + WSB_FBHI);
    const ushort* FBLO = (const ushort*)((const char*)ws + WSB_FBLO);
    const ushort* CB1  = (const ushort*)((const char*)ws + WSB_CB1);
    uint* Tb = exchbuf + w * 384;        /* 16 x 12 uints */
    uint* Mb = Tb + 192;                 /* 16 x 24 ushorts */

    /* loop-invariant per-lane state (one graph) */
    const float alpha = alpha_sh, oma = 1.f - alpha;
    const short8 Aadj = *(const short8*)&adjA[l][0];
    const f32x4 x2v = *(const f32x4*)&x2s[ig * 4];
    const f32x4 c1v = *(const f32x4*)&c1s[ig * 4];
    const f32x4 rsv = *(const f32x4*)&rss[ig * 4];

    #pragma unroll 1
    for (int kk = 0; kk < 8; ++kk) {
        const int k = kk * 4 + w;
        f32x4 acc = {0.f, 0.f, 0.f, 0.f};
        #pragma unroll
        for (int s = 0; s < 4; ++s) {
            const short8 Bh = *(const short8*)(FBHI + ((k * 4 + s) * 64 + l) * 8);
            const short8 Bl = *(const short8*)(FBLO + ((k * 4 + s) * 64 + l) * 8);
            const short8 Ah = *(const short8*)&xA[0][s][l][0];
            const short8 Al = *(const short8*)&xA[1][s][l][0];
            acc = mfma16(Ah, Bh, acc);
            acc = mfma16(Al, Bh, acc);
            acc = mfma16(Ah, Bl, acc);
        }
        const float f2v  = f2_s[jl][k];
        const float cctv = cct_s[k * 16 + jl];
        const float cc2v = cc2_s[k * 16 + jl];
        const short8 C1f = *(const short8*)(CB1 + (k * 64 + l) * 8);

        float Chat[4], rc[4];
        #pragma unroll
        for (int r = 0; r < 4; ++r) {
            float M = x2v[r] + f2v - 2.f * acc[r];
            rc[r] = rsv[r] * cctv;
            float gw0 = c1v[r] + cc2v - 2.f * rc[r];
            Chat[r] = SC_ * (oma * M + alpha * gw0);
        }
        /* log2-domain sinkhorn, 2 iters; h_sub=1/16 -> lp2=-4 */
        float G = 0.f, Fh[4];
        #pragma unroll
        for (int it = 0; it < 2; ++it) {
            #pragma unroll
            for (int r = 0; r < 4; ++r) {
                float a = G - Chat[r];
                float m = rowmax16(a);
                float e = exp2f(a - m);
                float S = rowsum16(e);
                Fh[r] = -4.f - m - log2f(S);
            }
            float diff[4];
            #pragma unroll
            for (int r = 0; r < 4; ++r) diff[r] = Fh[r] - Chat[r];
            float m2 = fmaxf(fmaxf(diff[0], diff[1]), fmaxf(diff[2], diff[3]));
            m2 = fmaxf(m2, __shfl_xor(m2, 16));
            m2 = fmaxf(m2, __shfl_xor(m2, 32));
            float S2 = 0.f;
            #pragma unroll
            for (int r = 0; r < 4; ++r) S2 += exp2f(diff[r] - m2);
            S2 += __shfl_xor(S2, 16);
            S2 += __shfl_xor(S2, 32);
            G = lq2 - m2 - log2f(S2);
        }
        float Tv[4];
        #pragma unroll
        for (int r = 0; r < 4; ++r) Tv[r] = exp2f(Fh[r] + G - Chat[r]);

        /* T exchange: packed bf16 via v_cvt_pk. Tb[col*12 + row/2] */
        Tb[jl * 12 + ig * 2]     = cvtpk_bf16(Tv[0], Tv[1]);
        Tb[jl * 12 + ig * 2 + 1] = cvtpk_bf16(Tv[2], Tv[3]);
        /* B-frag: lane (kg=ig, j=jl) needs T[(ig&1)*8 + e][jl];
           Aadj kg>=2 holds adj_lo -> one MFMA = adj_hi@T + adj_lo@T */
        const short8 Bt = *(const short8*)&Tb[jl * 12 + (ig & 1) * 4];
        f32x4 tmpv = mfma16(Aadj, Bt, (f32x4){0.f, 0.f, 0.f, 0.f});

        /* tmp exchange: bf16 row-major [16][24] ushorts */
        ushort* Mbs = (ushort*)Mb;
        #pragma unroll
        for (int r = 0; r < 4; ++r)
            Mbs[(ig * 4 + r) * 24 + jl] = bf16rne(tmpv[r]);
        const short8 Atm = *(const short8*)&Mbs[jl * 24 + (ig & 1) * 8];
        f32x4 cr = mfma16(Atm, C1f, (f32x4){0.f, 0.f, 0.f, 0.f});

        float dot = 0.f;
        #pragma unroll
        for (int r = 0; r < 4; ++r) {
            float fc = Chat[r] * ISC_ + 2.f * alpha * (rc[r] - cr[r]);
            dot = fmaf(Tv[r], fc, dot);
        }
        dot = rowsum16(dot);
        dot += __shfl_xor(dot, 16);
        dot += __shfl_xor(dot, 32);
        if (l == 0) out[blk * K_ + k] = dot;
    }
}

extern "C" void kernel_launch(void* const* d_in, const int* in_sizes, int n_in,
                              void* d_out, int out_size, void* d_ws, size_t ws_size,
                              hipStream_t stream) {
    (void)in_sizes; (void)n_in; (void)out_size; (void)ws_size;
    const float* adj      = (const float*)d_in[0];
    const float* features = (const float*)d_in[1];
    const int*   idxs     = (const int*)  d_in[2];
    const float* C_up     = (const float*)d_in[3];
    const float* Ff       = (const float*)d_in[4];
    const float* h_logits = (const float*)d_in[5];
    const float* w1       = (const float*)d_in[6];
    const float* b1       = (const float*)d_in[7];
    const float* w2       = (const float*)d_in[8];
    const float* b2       = (const float*)d_in[9];
    float* out = (float*)d_out;
    float* ws  = (float*)d_ws;

    hipLaunchKernelGGL(init_fb, dim3(128), dim3(512), 0, stream, Ff, ws);
    hipLaunchKernelGGL(init_small, dim3(1), dim3(1024), 0, stream, C_up, Ff, h_logits, w1, ws);
    hipLaunchKernelGGL(fgw_main, dim3(B_), dim3(256), 0, stream,
                       adj, features, idxs, b1, w2, b2, ws, out);
}